// Round 3
// baseline (1745.715 us; speedup 1.0000x reference)
//
#include <hip/hip_runtime.h>
#include <stdint.h>

#define NOBJ 20000
#define NTRI 100000

typedef unsigned short ushort_t;
typedef __attribute__((ext_vector_type(8))) short short8;
typedef __attribute__((ext_vector_type(4))) float float4v;

enum { MODE_H = 0, MODE_T = 1, MODE_G = 2, MODE_OBJ = 3, MODE_PRED = 4 };

__device__ __forceinline__ ushort_t f2bf(float f) {
    union { float f; unsigned int i; } x;
    x.f = f;
    unsigned int r = x.i + 0x7fffu + ((x.i >> 16) & 1u);  // RNE
    return (ushort_t)(r >> 16);
}

__device__ __forceinline__ void gload_lds16(const ushort_t* g, short8* l) {
    __builtin_amdgcn_global_load_lds((const __attribute__((address_space(1))) void*)g,
                                     (__attribute__((address_space(3))) void*)l,
                                     16, 0, 0);
}

// fp32 -> bf16 conversion, 4 elements/thread
__global__ void __launch_bounds__(256) cvt_k(const float* __restrict__ src,
                                             ushort_t* __restrict__ dst, int n4) {
    int i = blockIdx.x * 256 + threadIdx.x;
    if (i >= n4) return;
    const float4* s4 = (const float4*)src;
    float4 v = s4[i];
    ushort_t o[4] = {f2bf(v.x), f2bf(v.y), f2bf(v.z), f2bf(v.w)};
    *(uint64_t*)(dst + 4 * (size_t)i) = *(const uint64_t*)o;
}

// Generic 128x128 tile MFMA GEMM computing C[m][n] = sum_k A[m][k]*B[n][k]
// (A: M x K row-major bf16, B: N x K row-major bf16), mode-specialized
// A-source (fused gather for MODE_H) and epilogue.
template <int MODE>
__global__ void __launch_bounds__(256)
gtc_gemm(const ushort_t* __restrict__ A, const ushort_t* __restrict__ Bw,
         const float* __restrict__ bias,
         const ushort_t* __restrict__ A2, const ushort_t* __restrict__ B2,
         const float* __restrict__ bias2,
         const int* __restrict__ edges,
         const ushort_t* __restrict__ objv, const ushort_t* __restrict__ predv,
         float* __restrict__ pooled,
         const float* __restrict__ addend,
         void* __restrict__ outv,
         int M, int K)
{
    // LDS granule layout [kg][row], 16B granules, kg-major: fragment
    // ds_read_b128 is conflict-free.
    __shared__ short8 sA[1024];   // 16 KB
    __shared__ short8 sB[1024];   // 16 KB
    __shared__ int sIdx[128];
    __shared__ int oIdx[128];

    const int tid  = threadIdx.x;
    const int lane = tid & 63;
    const int wave = tid >> 6;
    const int wm   = wave & 1;
    const int wn   = wave >> 1;
    const int quad = lane >> 4;
    const int lr   = lane & 15;
    const int m0   = blockIdx.y * 128;
    const int n0   = blockIdx.x * 128;

    if (MODE == MODE_H) {
        if (tid < 128) {
            int t = m0 + tid;
            if (t >= M) t = M - 1;
            sIdx[tid] = edges[2 * t];
            oIdx[tid] = edges[2 * t + 1];
        }
        __syncthreads();
    }

    float4v acc[4][4];
#pragma unroll
    for (int i = 0; i < 4; ++i)
#pragma unroll
        for (int j = 0; j < 4; ++j)
            acc[i][j] = (float4v){0.f, 0.f, 0.f, 0.f};

    const int npass = (MODE == MODE_OBJ) ? 2 : 1;
    for (int pass = 0; pass < npass; ++pass) {
        const ushort_t* Ap = (pass == 0) ? A : A2;
        const ushort_t* Bp = (pass == 0) ? Bw : B2;

        for (int k0 = 0; k0 < K; k0 += 64) {
            __syncthreads();  // previous tile's compute done before restage
            // ---- stage A tile (128 rows x 64 k) ----
#pragma unroll
            for (int i = 0; i < 4; ++i) {
                int g  = i * 256 + tid;       // granule = kg*128 + m
                int kg = g >> 7;              // wave-uniform
                int m  = g & 127;
                int krow = k0 + kg * 8;
                const ushort_t* src;
                if (MODE == MODE_H) {
                    int t = m0 + m;
                    if (t >= M) t = M - 1;
                    if (krow < 512)
                        src = objv + (size_t)sIdx[m] * 512 + krow;
                    else if (krow < 1024)
                        src = predv + (size_t)t * 512 + (krow - 512);
                    else
                        src = objv + (size_t)oIdx[m] * 512 + (krow - 1024);
                } else {
                    int r = m0 + m;
                    if (r >= M) r = M - 1;
                    src = Ap + (size_t)r * K + krow;
                }
                gload_lds16(src, &sA[g]);
            }
            // ---- stage B tile (128 n x 64 k) ----
#pragma unroll
            for (int i = 0; i < 4; ++i) {
                int g  = i * 256 + tid;
                int kg = g >> 7;
                int n  = g & 127;
                gload_lds16(Bp + (size_t)(n0 + n) * K + k0 + kg * 8, &sB[g]);
            }
            __syncthreads();  // staging drained

#pragma unroll
            for (int kk = 0; kk < 2; ++kk) {
                short8 af[4], bfv[4];
#pragma unroll
                for (int t = 0; t < 4; ++t)
                    af[t] = sA[(kk * 4 + quad) * 128 + wm * 64 + t * 16 + lr];
#pragma unroll
                for (int t = 0; t < 4; ++t)
                    bfv[t] = sB[(kk * 4 + quad) * 128 + wn * 64 + t * 16 + lr];
#pragma unroll
                for (int ti = 0; ti < 4; ++ti)
#pragma unroll
                    for (int tj = 0; tj < 4; ++tj)
                        acc[ti][tj] = __builtin_amdgcn_mfma_f32_16x16x32_bf16(
                            af[ti], bfv[tj], acc[ti][tj], 0, 0, 0);
            }
        }

        if (MODE == MODE_OBJ && pass == 0) {
            // acc = relu(acc + c2[col]) between the two fused GEMMs
#pragma unroll
            for (int tj = 0; tj < 4; ++tj) {
                float b = bias[n0 + wn * 64 + tj * 16 + lr];
#pragma unroll
                for (int ti = 0; ti < 4; ++ti)
#pragma unroll
                    for (int r = 0; r < 4; ++r)
                        acc[ti][tj][r] = fmaxf(acc[ti][tj][r] + b, 0.f);
            }
        }
    }

    // ---- epilogue ----
    int region = 0;
    if (MODE == MODE_T) region = (int)(blockIdx.x >> 2);  // 0:s 1:p 2:o

    float bcol[4];
#pragma unroll
    for (int tj = 0; tj < 4; ++tj) {
        int col = n0 + wn * 64 + tj * 16 + lr;
        const float* bptr = (MODE == MODE_OBJ) ? bias2 : bias;
        bcol[tj] = bptr[col];
    }

#pragma unroll
    for (int ti = 0; ti < 4; ++ti) {
#pragma unroll
        for (int r = 0; r < 4; ++r) {
            int row = m0 + wm * 64 + ti * 16 + quad * 4 + r;
            if (row >= M) continue;
            int eidx = 0;
            if (MODE == MODE_T && region != 1)
                eidx = (region == 0) ? edges[2 * row] : edges[2 * row + 1];
#pragma unroll
            for (int tj = 0; tj < 4; ++tj) {
                int col = n0 + wn * 64 + tj * 16 + lr;
                float v = acc[ti][tj][r];
                if (MODE == MODE_H || MODE == MODE_G || MODE == MODE_T)
                    v = fmaxf(v + bcol[tj], 0.f);
                else
                    v = v + bcol[tj];

                if (MODE == MODE_H || MODE == MODE_G) {
                    ((ushort_t*)outv)[(size_t)row * 512 + col] = f2bf(v);  // bf16 intermediate
                } else if (MODE == MODE_T) {
                    int c = col & 511;
                    if (region == 1)
                        ((float*)outv)[(size_t)row * 512 + c] = v;  // partial new_p -> out_p
                    else
                        atomicAdd(&pooled[(size_t)eidx * 512 + c], v);
                } else if (MODE == MODE_OBJ) {
                    ((float*)outv)[(size_t)row * 512 + col] = v;
                } else {  // MODE_PRED
                    v += addend[(size_t)row * 512 + col];
                    ((float*)outv)[(size_t)row * 512 + col] = v;
                }
            }
        }
    }
}

__global__ void counts_k(const int* __restrict__ edges, float* __restrict__ counts, int n2) {
    int i = blockIdx.x * 256 + threadIdx.x;
    if (i < n2) atomicAdd(&counts[edges[i]], 1.0f);
}

__global__ void norm_k(const float* __restrict__ pooled, const float* __restrict__ counts,
                       ushort_t* __restrict__ pooledn) {
    int i = blockIdx.x * 256 + threadIdx.x;  // NOBJ*512 threads exactly
    float c = fmaxf(counts[i >> 9], 1.0f);
    pooledn[i] = f2bf(pooled[i] / c);
}

extern "C" void kernel_launch(void* const* d_in, const int* in_sizes, int n_in,
                              void* d_out, int out_size, void* d_ws, size_t ws_size,
                              hipStream_t stream) {
    const float* obj    = (const float*)d_in[0];
    const float* pred   = (const float*)d_in[1];
    const int*   edges  = (const int*)d_in[2];
    const float* W1     = (const float*)d_in[3];
    const float* b1     = (const float*)d_in[4];
    const float* W2     = (const float*)d_in[5];
    const float* b2     = (const float*)d_in[6];
    const float* V1     = (const float*)d_in[7];
    const float* c1     = (const float*)d_in[8];
    const float* V2     = (const float*)d_in[9];
    const float* c2     = (const float*)d_in[10];
    const float* Pobj   = (const float*)d_in[11];
    const float* pbobj  = (const float*)d_in[12];
    const float* Ppred  = (const float*)d_in[13];
    const float* pbpred = (const float*)d_in[14];

    // ---- workspace layout (total 230,602,880 B — shrunk from 312 MB; the
    // round-2 failure signature pointed at ws overflow corrupting the heap) ----
    char* ws = (char*)d_ws;
    ushort_t* h       = (ushort_t*)(ws + 0);              // 102,400,000 B (dead after GEMM2)
    ushort_t* bfPred  = (ushort_t*)(ws + 102400000);      // 102,400,000 B
    ushort_t* bfObj   = (ushort_t*)(ws + 204800000);      //  20,480,000 B
    ushort_t* bfW1    = (ushort_t*)(ws + 225280000);      //   1,572,864 B
    ushort_t* bfW2    = (ushort_t*)(ws + 226852864);      //   1,572,864 B
    ushort_t* bfV1    = (ushort_t*)(ws + 228425728);      //     524,288 B
    ushort_t* bfV2    = (ushort_t*)(ws + 228950016);      //     524,288 B
    ushort_t* bfPobj  = (ushort_t*)(ws + 229474304);      //     524,288 B
    ushort_t* bfPpred = (ushort_t*)(ws + 229998592);      //     524,288 B
    float*    counts  = (float*)   (ws + 230522880);      //      80,000 B
    // aliases into the dead h region (only used after GEMM2 completes):
    ushort_t* pooledn = (ushort_t*)(ws + 0);              //  20,480,000 B
    ushort_t* gbuf    = (ushort_t*)(ws + 20480000);       //  20,480,000 B

    float* out_obj = (float*)d_out;
    float* out_p   = out_obj + (size_t)NOBJ * 512;
    // pooled (fp32 accumulators) lives in the out_obj region of d_out:
    // it is consumed by norm_k before MODE_OBJ overwrites out_obj.
    float* pooled  = out_obj;

    hipMemsetAsync(pooled, 0, 40960000, stream);
    hipMemsetAsync(counts, 0, 80000, stream);

    // fp32 -> bf16 conversions
    cvt_k<<<dim3(10000), dim3(256), 0, stream>>>(obj,   bfObj,   10240000/4);
    cvt_k<<<dim3(50000), dim3(256), 0, stream>>>(pred,  bfPred,  51200000/4);
    cvt_k<<<dim3(768),   dim3(256), 0, stream>>>(W1,    bfW1,    786432/4);
    cvt_k<<<dim3(768),   dim3(256), 0, stream>>>(W2,    bfW2,    786432/4);
    cvt_k<<<dim3(256),   dim3(256), 0, stream>>>(V1,    bfV1,    262144/4);
    cvt_k<<<dim3(256),   dim3(256), 0, stream>>>(V2,    bfV2,    262144/4);
    cvt_k<<<dim3(256),   dim3(256), 0, stream>>>(Pobj,  bfPobj,  262144/4);
    cvt_k<<<dim3(256),   dim3(256), 0, stream>>>(Ppred, bfPpred, 262144/4);

    counts_k<<<dim3(782), dim3(256), 0, stream>>>(edges, counts, 2 * NTRI);

    // GEMM1: h = relu(gather(cur_t) @ W1^T + b1)    (100000 x 512, K=1536)
    gtc_gemm<MODE_H><<<dim3(4, 782), dim3(256), 0, stream>>>(
        nullptr, bfW1, b1, nullptr, nullptr, nullptr,
        edges, bfObj, bfPred, nullptr, nullptr, h, NTRI, 1536);

    // GEMM2: new_t = relu(h @ W2^T + b2); scatter s/o into pooled, p -> out_p
    gtc_gemm<MODE_T><<<dim3(12, 782), dim3(256), 0, stream>>>(
        h, bfW2, b2, nullptr, nullptr, nullptr,
        edges, nullptr, nullptr, pooled, nullptr, out_p, NTRI, 512);

    // pooled / max(counts,1) -> bf16  (pooledn aliases dead h region)
    norm_k<<<dim3(40000), dim3(256), 0, stream>>>(pooled, counts, pooledn);

    // GEMM3: g = relu(pooledn @ V1^T + c1)          (20000 x 512, K=512)
    gtc_gemm<MODE_G><<<dim3(4, 157), dim3(256), 0, stream>>>(
        pooledn, bfV1, c1, nullptr, nullptr, nullptr,
        nullptr, nullptr, nullptr, nullptr, nullptr, gbuf, NOBJ, 512);

    // GEMM4+5 fused: out_obj = relu(g @ V2^T + c2) + obj @ P_obj^T + pb_obj
    // (overwrites pooled region — pooled is dead after norm_k)
    gtc_gemm<MODE_OBJ><<<dim3(4, 157), dim3(256), 0, stream>>>(
        gbuf, bfV2, c2, bfObj, bfPobj, pbobj,
        nullptr, nullptr, nullptr, nullptr, nullptr, out_obj, NOBJ, 512);

    // GEMM6: out_p = new_p + pred @ P_pred^T + pb_pred  (in-place addend)
    gtc_gemm<MODE_PRED><<<dim3(4, 782), dim3(256), 0, stream>>>(
        bfPred, bfPpred, pbpred, nullptr, nullptr, nullptr,
        nullptr, nullptr, nullptr, nullptr, out_p, out_p, NTRI, 512);
}